// Round 3
// baseline (15.242 us; speedup 1.0000x reference)
//
#include <hip/hip_runtime.h>

// x: (16, 48, 10, 128, 128) f32.  out: (16, 10, 128, 128) f32.
// out[b,k,h,w] = p_k * LA(b,h,w) + q_k * x[b,47,0,h,w]
// LA = (1-mu)^48 * mean_t(x_t) + mu * sum_t (1-mu)^(47-t) x_t   (feature 0 only)
//
// 4-way time-split: lane group of 4 covers t-quarters {0-11,12-23,24-35,36-47}
// of the SAME float4 pixel group; butterfly-combine with __shfl_xor(1,2).
// 262144 threads -> 1024 blocks -> 16 waves/CU (2x the TLP of R1/R2).

#define NB 16
#define NT 48
#define NF 10
#define HW (128 * 128)
#define NK 10
#define QUART 12

struct Coefs {
    float w[NT];
    float p[NK];
    float q[NK];
};

constexpr Coefs make_coefs() {
    Coefs c{};
    const double mu = 2.0 / 11.0;
    const double om = 1.0 - mu;
    double pow48 = 1.0;
    for (int i = 0; i < NT; ++i) pow48 *= om;
    for (int t = 0; t < NT; ++t) {
        double e = 1.0;
        for (int i = 0; i < NT - 1 - t; ++i) e *= om;   // (1-mu)^(47-t)
        c.w[t] = (float)(pow48 / (double)NT + mu * e);
    }
    // a_{-1}=x47 (p=0,q=1), a_0=LA (p=1,q=0); a_{k+1}=mu*a_{k-1}+(1-mu)*a_k
    double pm1 = 0.0, p0 = 1.0, qm1 = 1.0, q0 = 0.0;
    for (int k = 0; k < NK; ++k) {
        c.p[k] = (float)p0;
        c.q[k] = (float)q0;
        double pn = mu * pm1 + om * p0;
        double qn = mu * qm1 + om * q0;
        pm1 = p0; p0 = pn;
        qm1 = q0; q0 = qn;
    }
    return c;
}

constexpr Coefs CO = make_coefs();

__global__ __launch_bounds__(256) void ema_kernel(const float* __restrict__ x,
                                                  float* __restrict__ out) {
    const int tid = blockIdx.x * blockDim.x + threadIdx.x;  // 0 .. NB*HW/4*4 - 1
    const int h   = tid & 3;        // which t-quarter
    const int p   = tid >> 2;       // float4 pixel-group id: 0 .. NB*HW/4 - 1
    const int b   = p >> 12;        // / (HW/4 = 4096)
    const int c4  = p & 4095;

    const int TS = NF * HW / 4;     // float4 stride between time planes (40960)

    const float4* xp =
        reinterpret_cast<const float4*>(x + (size_t)b * NT * NF * HW) +
        (size_t)h * QUART * TS + c4;

    float4 la  = make_float4(0.f, 0.f, 0.f, 0.f);
    float4 x47 = make_float4(0.f, 0.f, 0.f, 0.f);
#pragma unroll
    for (int t = 0; t < QUART; ++t) {
        float4 v = xp[(size_t)t * TS];
        const float wt = CO.w[h * QUART + t];   // h runtime -> rodata load, cached
        la.x = fmaf(wt, v.x, la.x);
        la.y = fmaf(wt, v.y, la.y);
        la.z = fmaf(wt, v.z, la.z);
        la.w = fmaf(wt, v.w, la.w);
        if (t == QUART - 1 && h == 3) x47 = v;  // only h=3 sees t=47
    }

    // butterfly combine across the 4-lane group
#pragma unroll
    for (int m = 1; m <= 2; m <<= 1) {
        la.x += __shfl_xor(la.x, m);
        la.y += __shfl_xor(la.y, m);
        la.z += __shfl_xor(la.z, m);
        la.w += __shfl_xor(la.w, m);
        x47.x += __shfl_xor(x47.x, m);
        x47.y += __shfl_xor(x47.y, m);
        x47.z += __shfl_xor(x47.z, m);
        x47.w += __shfl_xor(x47.w, m);
    }

    // output assignment: h=0 -> k{0,1,2}, h=1 -> k{3,4,5}, h=2 -> k{6,7}, h=3 -> k{8,9}
    const int cnt = (h < 2) ? 3 : 2;
    const int st  = (h < 2) ? h * 3 : 6 + (h - 2) * 2;
    float4* op = reinterpret_cast<float4*>(out + (size_t)b * NK * HW) + c4;
#pragma unroll
    for (int j = 0; j < 3; ++j) {
        if (j < cnt) {
            const int k = st + j;
            const float pk = CO.p[k];
            const float qk = CO.q[k];
            float4 o;
            o.x = fmaf(pk, la.x, qk * x47.x);
            o.y = fmaf(pk, la.y, qk * x47.y);
            o.z = fmaf(pk, la.z, qk * x47.z);
            o.w = fmaf(pk, la.w, qk * x47.w);
            op[(size_t)k * (HW / 4)] = o;
        }
    }
}

extern "C" void kernel_launch(void* const* d_in, const int* in_sizes, int n_in,
                              void* d_out, int out_size, void* d_ws, size_t ws_size,
                              hipStream_t stream) {
    const float* x = (const float*)d_in[0];
    float* out = (float*)d_out;
    const int total = NB * (HW / 4) * 4;  // 262144 threads
    const int block = 256;
    const int grid  = total / block;      // 1024 blocks -> 4 blocks/CU
    ema_kernel<<<grid, block, 0, stream>>>(x, out);
}